// Round 9
// baseline (25.367 us; speedup 1.0000x reference)
//
#include <hip/hip_runtime.h>
#include <stdint.h>

#define NV 4096

typedef __attribute__((ext_vector_type(8))) short bf16x8;
typedef __attribute__((ext_vector_type(4))) float f32x4;

__device__ __forceinline__ unsigned short f2bf(float f) {
  union { float f; unsigned int u; } v; v.f = f;
  unsigned int r = v.u + 0x7FFF + ((v.u >> 16) & 1);  // RNE
  return (unsigned short)(r >> 16);
}

// fused prep: blocks 0..1023 convert feature_map f32->bf16 (8 elems/thread);
// blocks 1024..1295 permute weights (64 x 1088, f=c*17+k) -> Wb[k][o][c] bf16.
__global__ __launch_bounds__(256)
void prep(const float* __restrict__ fm, const float* __restrict__ w,
          unsigned short* __restrict__ fmb, unsigned short* __restrict__ wb) {
  int blk = blockIdx.x;
  if (blk < 1024) {
    int i = (blk * 256 + threadIdx.x) * 8;
    float4 v0 = *(const float4*)(fm + i);
    float4 v1 = *(const float4*)(fm + i + 4);
    ushort4 o0, o1;
    o0.x = f2bf(v0.x); o0.y = f2bf(v0.y); o0.z = f2bf(v0.z); o0.w = f2bf(v0.w);
    o1.x = f2bf(v1.x); o1.y = f2bf(v1.y); o1.z = f2bf(v1.z); o1.w = f2bf(v1.w);
    *(ushort4*)(fmb + i) = o0;
    *(ushort4*)(fmb + i + 4) = o1;
  } else {
    int t = (blk - 1024) * 256 + threadIdx.x;  // 0..69631 (= 17*64*64)
    int c = t & 63;
    int o = (t >> 6) & 63;
    int k = t >> 12;
    wb[t] = f2bf(w[o * 1088 + c * 17 + k]);
  }
}

// High-occupancy gather-GEMM (R8 design, staging/F issue-order race FIXED):
//  block = 256 thr = 4 waves = 2 row-groups x 2 channel-halves; 32 rows/block;
//  grid 1024 -> 4 blocks/CU -> 4 waves/SIMD.
//  Per-slot 8KB W double-buffer staged via global_load_lds (pre-swizzled src);
//  per-slot raw s_barrier + counted vmcnt(1).  Issue order within each step is
//  pinned with sched_barrier(0) between STAGE and LOADF so the counted vmcnt
//  provably drains staging while the F gather stays in flight.
__global__ __launch_bounds__(256, 4)
void conv_main(const int* __restrict__ nbr, const unsigned short* __restrict__ fmb,
               const unsigned short* __restrict__ wb, const float* __restrict__ bias,
               float* __restrict__ out) {
  __shared__ unsigned short smem[2][4096];   // 2 x 8KB W slot buffers

  const int bid = blockIdx.x;
  const int b = bid & 7;               // batch == XCD (bijective: 1024%8==0)
  const int tile = bid >> 3;           // 0..127 (32-row tiles)
  const int tid = threadIdx.x;
  const int lane = tid & 63;
  const int lm = lane & 15;
  const int lk = lane >> 4;
  const int w4 = tid >> 6;             // wave 0..3
  const int rg = w4 >> 1;              // row-group 0..1 (16 rows each)
  const int h = w4 & 1;                // channel half

  const int row = tile * 32 + rg * 16 + lm;
  const bf16x8* fb8 = (const bf16x8*)(fmb + (size_t)b * NV * 64);
  const int fsl = h * 4 + lk;          // this lane's 16B segment of a row

  // 16 neighbor indices for this lane's row
  const int4* q = (const int4*)(nbr + ((size_t)b * NV + row) * 16);
  const int4 ia = q[0], ib = q[1], ic = q[2], id = q[3];

  // swizzled W read offset (bytes): row o = n*16+lm, seg fsl ^ (o&7)
  const int offW = lm * 128 + ((fsl ^ (lm & 7)) << 4);

  f32x4 acc0{0,0,0,0}, acc1{0,0,0,0}, acc2{0,0,0,0}, acc3{0,0,0,0};
  bf16x8 FX, FY, FZ;

#define SBR __builtin_amdgcn_sched_barrier(0)
#define MFMA __builtin_amdgcn_mfma_f32_16x16x32_bf16

  // stage W slot -> LDS buf; src pre-swizzled so linear dst + swizzled read match
#define STAGE(SLOT, BUF) {                                                  \
    _Pragma("unroll")                                                       \
    for (int i_ = 0; i_ < 2; ++i_) {                                        \
      int t_ = i_ * 256 + tid;                                              \
      int o_ = t_ >> 3, s_ = t_ & 7;                                        \
      const unsigned short* src_ =                                          \
          wb + (size_t)(SLOT) * 4096 + o_ * 64 + ((s_ ^ (o_ & 7)) << 3);    \
      unsigned short* dst_ = &smem[BUF][t_ * 8];                            \
      __builtin_amdgcn_global_load_lds(                                     \
          (const __attribute__((address_space(1))) void*)src_,              \
          (__attribute__((address_space(3))) void*)dst_, 16, 0, 0);         \
    }                                                                       \
  }

#define LOADF(REG, SV) { F##REG = (fb8 + (size_t)(SV) * 8)[fsl]; }

#define MMA(REG, BUF) {                                                     \
    const char* bp_ = (const char*)smem[BUF];                               \
    bf16x8 W0 = *(const bf16x8*)(bp_ + 0 * 2048 + offW);                    \
    bf16x8 W1 = *(const bf16x8*)(bp_ + 1 * 2048 + offW);                    \
    bf16x8 W2 = *(const bf16x8*)(bp_ + 2 * 2048 + offW);                    \
    bf16x8 W3 = *(const bf16x8*)(bp_ + 3 * 2048 + offW);                    \
    acc0 = MFMA(F##REG, W0, acc0, 0, 0, 0);                                 \
    acc1 = MFMA(F##REG, W1, acc1, 0, 0, 0);                                 \
    acc2 = MFMA(F##REG, W2, acc2, 0, 0, 0);                                 \
    acc3 = MFMA(F##REG, W3, acc3, 0, 0, 0);                                 \
  }

  // slot -> source vertex (compile-time)
#define SV0 row
#define SV1 ia.x
#define SV2 ia.y
#define SV3 ia.z
#define SV4 ia.w
#define SV5 ib.x
#define SV6 ib.y
#define SV7 ib.z
#define SV8 ib.w
#define SV9 ic.x
#define SV10 ic.y
#define SV11 ic.z
#define SV12 ic.w
#define SV13 id.x
#define SV14 id.y
#define SV15 id.z
#define SV16 id.w

  // prologue: W0 staged | SBR | F0,F1 issued | vmcnt(2) drains W0 only
  STAGE(0, 0);
  SBR;
  LOADF(X, SV0);
  LOADF(Y, SV1);
  SBR; asm volatile("s_waitcnt vmcnt(2)" ::: "memory"); SBR;
  __builtin_amdgcn_s_barrier(); SBR;

  // step k: STAGE W(k+1) | SBR | F(k+2) | MMA slot k | vmcnt(1) | barrier.
  // queue at vmcnt(1): [F(k+1), Wa, Wb, F(k+2)] -> drains F(k+1)+staging,
  // keeps F(k+2) in flight.
#define STEPK(K, RCUR, RNXT, SVN)                                           \
    STAGE((K) + 1, ((K) + 1) & 1);                                          \
    SBR;                                                                    \
    LOADF(RNXT, SVN);                                                       \
    MMA(RCUR, (K) & 1);                                                     \
    SBR; asm volatile("s_waitcnt vmcnt(1)" ::: "memory"); SBR;              \
    __builtin_amdgcn_s_barrier(); SBR;

  STEPK(0,  X, Z, SV2);
  STEPK(1,  Y, X, SV3);
  STEPK(2,  Z, Y, SV4);
  STEPK(3,  X, Z, SV5);
  STEPK(4,  Y, X, SV6);
  STEPK(5,  Z, Y, SV7);
  STEPK(6,  X, Z, SV8);
  STEPK(7,  Y, X, SV9);
  STEPK(8,  Z, Y, SV10);
  STEPK(9,  X, Z, SV11);
  STEPK(10, Y, X, SV12);
  STEPK(11, Z, Y, SV13);
  STEPK(12, X, Z, SV14);
  STEPK(13, Y, X, SV15);
  STEPK(14, Z, Y, SV16);
  // k=15: stage W16, no new F, full drain (order-robust vmcnt(0))
  STAGE(16, 0);
  MMA(X, 1);
  SBR; asm volatile("s_waitcnt vmcnt(0)" ::: "memory"); SBR;
  __builtin_amdgcn_s_barrier(); SBR;
  // k=16: last slot, no stage, no barrier
  MMA(Y, 0);

#undef STEPK
#undef MMA
#undef LOADF
#undef STAGE
#undef MFMA
#undef SBR

  // reduce h-pairs through LDS (W buffers dead), then epilogue by h==0 waves
  __syncthreads();
  if (h == 1) {
    float* rp = (float*)smem + rg * 1024 + lane * 4;
    *(f32x4*)(rp + 0 * 256) = acc0;
    *(f32x4*)(rp + 1 * 256) = acc1;
    *(f32x4*)(rp + 2 * 256) = acc2;
    *(f32x4*)(rp + 3 * 256) = acc3;
  }
  __syncthreads();
  if (h == 0) {
    const float* rp = (const float*)smem + rg * 1024 + lane * 4;
    acc0 += *(const f32x4*)(rp + 0 * 256);
    acc1 += *(const f32x4*)(rp + 1 * 256);
    acc2 += *(const f32x4*)(rp + 2 * 256);
    acc3 += *(const f32x4*)(rp + 3 * 256);

    const float bv0 = bias[lm];
    const float bv1 = bias[16 + lm];
    const float bv2 = bias[32 + lm];
    const float bv3 = bias[48 + lm];
    float* op = out + (size_t)b * NV * 64;
    const int gv = tile * 32 + rg * 16 + lk * 4;
    #pragma unroll
    for (int r = 0; r < 4; ++r) {
      float* orow = op + (size_t)(gv + r) * 64;
      orow[lm]      = fmaxf(acc0[r] + bv0, 0.f);
      orow[16 + lm] = fmaxf(acc1[r] + bv1, 0.f);
      orow[32 + lm] = fmaxf(acc2[r] + bv2, 0.f);
      orow[48 + lm] = fmaxf(acc3[r] + bv3, 0.f);
    }
  }
}

extern "C" void kernel_launch(void* const* d_in, const int* in_sizes, int n_in,
                              void* d_out, int out_size, void* d_ws, size_t ws_size,
                              hipStream_t stream) {
  const int* nbr = (const int*)d_in[0];
  // d_in[1] = vertices (unused by the reference computation)
  const float* fm = (const float*)d_in[2];
  const float* w = (const float*)d_in[3];
  const float* bias = (const float*)d_in[4];
  float* out = (float*)d_out;

  unsigned short* fmb = (unsigned short*)d_ws;          // 8*4096*64 bf16 = 4 MB
  unsigned short* wb = fmb + (size_t)8 * NV * 64;       // 17*64*64 bf16

  prep<<<1296, 256, 0, stream>>>(fm, w, fmb, wb);
  conv_main<<<1024, 256, 0, stream>>>(nbr, fmb, wb, bias, out);
}

// Round 11
// 19.876 us; speedup vs baseline: 1.2762x; 1.2762x over previous
//
#include <hip/hip_runtime.h>
#include <stdint.h>

#define NV 4096

typedef __attribute__((ext_vector_type(8))) short bf16x8;
typedef __attribute__((ext_vector_type(4))) float f32x4;

__device__ __forceinline__ unsigned short f2bf(float f) {
  union { float f; unsigned int u; } v; v.f = f;
  unsigned int r = v.u + 0x7FFF + ((v.u >> 16) & 1);  // RNE
  return (unsigned short)(r >> 16);
}

// fused prep: blocks 0..1023 convert feature_map f32->bf16 (8 elems/thread);
// blocks 1024..1295 permute weights (64 x 1088, f=c*17+k) -> Wb[k][o][c] bf16.
__global__ __launch_bounds__(256)
void prep(const float* __restrict__ fm, const float* __restrict__ w,
          unsigned short* __restrict__ fmb, unsigned short* __restrict__ wb) {
  int blk = blockIdx.x;
  if (blk < 1024) {
    int i = (blk * 256 + threadIdx.x) * 8;
    float4 v0 = *(const float4*)(fm + i);
    float4 v1 = *(const float4*)(fm + i + 4);
    ushort4 o0, o1;
    o0.x = f2bf(v0.x); o0.y = f2bf(v0.y); o0.z = f2bf(v0.z); o0.w = f2bf(v0.w);
    o1.x = f2bf(v1.x); o1.y = f2bf(v1.y); o1.z = f2bf(v1.z); o1.w = f2bf(v1.w);
    *(ushort4*)(fmb + i) = o0;
    *(ushort4*)(fmb + i + 4) = o1;
  } else {
    int t = (blk - 1024) * 256 + threadIdx.x;  // 0..69631 (= 17*64*64)
    int c = t & 63;
    int o = (t >> 6) & 63;
    int k = t >> 12;
    wb[t] = f2bf(w[o * 1088 + c * 17 + k]);
  }
}

// LDS-gather GEMM: F rows are gathered block-cooperatively via global_load_lds
// (per-lane SOURCE addresses, lane-linear LDS dest): 8 consecutive lanes fetch
// one row's 128B contiguously -> guaranteed coalescing, independent of MFMA
// lane layout.  Consumers ds_read_b128 fragments with XOR swizzle baked into
// the staged source granule (involution).  W staged the same way (R9 pattern).
// Triple-buffered slots, stage k+2 at step k, counted vmcnt(4) + raw barrier.
// Block = 256 thr = 4 waves (2 row-groups x 2 ch-halves), 64 rows; grid 512.
__global__ __launch_bounds__(256, 2)
void conv_main(const int* __restrict__ nbr, const unsigned short* __restrict__ fmb,
               const unsigned short* __restrict__ wb, const float* __restrict__ bias,
               float* __restrict__ out) {
  __shared__ unsigned char smem[49152];  // W: 3x8KB @0, F: 3x8KB @24576

  const int bid = blockIdx.x;
  const int b = bid & 7;               // batch == XCD (512%8==0, bijective)
  const int tile = bid >> 3;           // 0..63
  const int tid = threadIdx.x;
  const int lane = tid & 63;
  const int lm = lane & 15;
  const int lk = lane >> 4;
  const int w4 = tid >> 6;             // wave 0..3
  const int rg = w4 >> 1;              // row-group 0..1 (32 rows)
  const int h = w4 & 1;                // channel half

  const int rbase = tile * 64;
  const bf16x8* fb8 = (const bf16x8*)(fmb + (size_t)b * NV * 64);

  // staging identity: thread t stages F granules t (row t>>3) and t+256
  // (row t>>3+32); 8 consecutive lanes cover one row's 128B contiguously.
  const int r0 = tid >> 3;             // 0..31
  const int c8 = tid & 7;
  const int swz = c8 ^ (r0 & 7);       // source-granule swizzle (r1&7 == r0&7)
  const int row0g = rbase + r0;
  const int row1g = rbase + r0 + 32;

  // neighbor indices for the two staged rows (8-lane redundant, L1-broadcast)
  const int4* q0 = (const int4*)(nbr + ((size_t)b * NV + row0g) * 16);
  const int4* q1 = (const int4*)(nbr + ((size_t)b * NV + row1g) * 16);
  const int4 i0a = q0[0], i0b = q0[1], i0c = q0[2], i0d = q0[3];
  const int4 i1a = q1[0], i1b = q1[1], i1c = q1[2], i1d = q1[3];

  // consumer read offsets (R9-verified math)
  const int fsl = h * 4 + lk;
  const int offW = lm * 128 + ((fsl ^ (lm & 7)) << 4);
  const int rowL0 = rg * 32 + lm;
  const int rowL1 = rg * 32 + 16 + lm;
  const int offA0 = rowL0 * 128 + ((fsl ^ (rowL0 & 7)) << 4);
  const int offA1 = rowL1 * 128 + ((fsl ^ (rowL1 & 7)) << 4);

  f32x4 accA0{0,0,0,0}, accA1{0,0,0,0}, accA2{0,0,0,0}, accA3{0,0,0,0};
  f32x4 accB0{0,0,0,0}, accB1{0,0,0,0}, accB2{0,0,0,0}, accB3{0,0,0,0};

#define SBR __builtin_amdgcn_sched_barrier(0)
#define MFMA __builtin_amdgcn_mfma_f32_16x16x32_bf16

  // 4 gload_lds per thread: 2 W granules + 2 F rows (sources pre-swizzled)
#define STAGE(SLOT, BUF, SVA, SVB) {                                        \
    _Pragma("unroll")                                                       \
    for (int i_ = 0; i_ < 2; ++i_) {                                        \
      int t_ = i_ * 256 + tid;                                              \
      int o_ = t_ >> 3, s_ = t_ & 7;                                        \
      const unsigned short* ws_ =                                           \
          wb + (SLOT) * 4096 + o_ * 64 + ((s_ ^ (o_ & 7)) << 3);            \
      __builtin_amdgcn_global_load_lds(                                     \
          (const __attribute__((address_space(1))) void*)ws_,               \
          (__attribute__((address_space(3))) void*)(smem + (BUF) * 8192 + t_ * 16), \
          16, 0, 0);                                                        \
    }                                                                       \
    {                                                                       \
      const bf16x8* fa_ = fb8 + (size_t)(SVA) * 8 + swz;                    \
      __builtin_amdgcn_global_load_lds(                                     \
          (const __attribute__((address_space(1))) void*)fa_,               \
          (__attribute__((address_space(3))) void*)(smem + 24576 + (BUF) * 8192 + tid * 16), \
          16, 0, 0);                                                        \
      const bf16x8* fbp_ = fb8 + (size_t)(SVB) * 8 + swz;                   \
      __builtin_amdgcn_global_load_lds(                                     \
          (const __attribute__((address_space(1))) void*)fbp_,              \
          (__attribute__((address_space(3))) void*)(smem + 24576 + (BUF) * 8192 + 4096 + tid * 16), \
          16, 0, 0);                                                        \
    }                                                                       \
  }

#define CONSUME(BUF) {                                                     \
    const char* wp_ = (const char*)smem + (BUF) * 8192;                    \
    const char* fp_ = (const char*)smem + 24576 + (BUF) * 8192;            \
    bf16x8 W0 = *(const bf16x8*)(wp_ + 0 * 2048 + offW);                   \
    bf16x8 W1 = *(const bf16x8*)(wp_ + 1 * 2048 + offW);                   \
    bf16x8 W2 = *(const bf16x8*)(wp_ + 2 * 2048 + offW);                   \
    bf16x8 W3 = *(const bf16x8*)(wp_ + 3 * 2048 + offW);                   \
    bf16x8 A0 = *(const bf16x8*)(fp_ + offA0);                             \
    bf16x8 A1 = *(const bf16x8*)(fp_ + offA1);                             \
    accA0 = MFMA(A0, W0, accA0, 0, 0, 0);                                  \
    accA1 = MFMA(A0, W1, accA1, 0, 0, 0);                                  \
    accA2 = MFMA(A0, W2, accA2, 0, 0, 0);                                  \
    accA3 = MFMA(A0, W3, accA3, 0, 0, 0);                                  \
    accB0 = MFMA(A1, W0, accB0, 0, 0, 0);                                  \
    accB1 = MFMA(A1, W1, accB1, 0, 0, 0);                                  \
    accB2 = MFMA(A1, W2, accB2, 0, 0, 0);                                  \
    accB3 = MFMA(A1, W3, accB3, 0, 0, 0);                                  \
  }

#define WAITBAR(N)                                                          \
    SBR; asm volatile("s_waitcnt vmcnt(" #N ")" ::: "memory"); SBR;         \
    __builtin_amdgcn_s_barrier(); SBR;

  // prologue: stage slots 0,1; drain slot 0 (leave slot 1 in flight)
  STAGE(0, 0, row0g, row1g); SBR;
  STAGE(1, 1, i0a.x, i1a.x); SBR;
  WAITBAR(4);

  // steady state: stage slot k+2 into buf (k+2)%3, consume buf k%3,
  // then wait vmcnt(4) (keeps k+2's 4 loads in flight) + barrier.
  STAGE(2, 2, i0a.y, i1a.y);  SBR; CONSUME(0); WAITBAR(4);   // k=0
  STAGE(3, 0, i0a.z, i1a.z);  SBR; CONSUME(1); WAITBAR(4);   // k=1
  STAGE(4, 1, i0a.w, i1a.w);  SBR; CONSUME(2); WAITBAR(4);   // k=2
  STAGE(5, 2, i0b.x, i1b.x);  SBR; CONSUME(0); WAITBAR(4);   // k=3
  STAGE(6, 0, i0b.y, i1b.y);  SBR; CONSUME(1); WAITBAR(4);   // k=4
  STAGE(7, 1, i0b.z, i1b.z);  SBR; CONSUME(2); WAITBAR(4);   // k=5
  STAGE(8, 2, i0b.w, i1b.w);  SBR; CONSUME(0); WAITBAR(4);   // k=6
  STAGE(9, 0, i0c.x, i1c.x);  SBR; CONSUME(1); WAITBAR(4);   // k=7
  STAGE(10, 1, i0c.y, i1c.y); SBR; CONSUME(2); WAITBAR(4);   // k=8
  STAGE(11, 2, i0c.z, i1c.z); SBR; CONSUME(0); WAITBAR(4);   // k=9
  STAGE(12, 0, i0c.w, i1c.w); SBR; CONSUME(1); WAITBAR(4);   // k=10
  STAGE(13, 1, i0d.x, i1d.x); SBR; CONSUME(2); WAITBAR(4);   // k=11
  STAGE(14, 2, i0d.y, i1d.y); SBR; CONSUME(0); WAITBAR(4);   // k=12
  STAGE(15, 0, i0d.z, i1d.z); SBR; CONSUME(1); WAITBAR(4);   // k=13
  STAGE(16, 1, i0d.w, i1d.w); SBR; CONSUME(2); WAITBAR(4);   // k=14
  CONSUME(0); WAITBAR(0);                                    // k=15, drain 16
  CONSUME(1);                                                // k=16

#undef WAITBAR
#undef CONSUME
#undef STAGE
#undef MFMA
#undef SBR

  // reduce h-pairs through LDS (buffers dead), epilogue by h==0 waves
  __syncthreads();
  if (h == 1) {
    float* rp = (float*)smem + rg * 2048 + lane * 4;
    *(f32x4*)(rp + 0 * 256) = accA0;
    *(f32x4*)(rp + 1 * 256) = accA1;
    *(f32x4*)(rp + 2 * 256) = accA2;
    *(f32x4*)(rp + 3 * 256) = accA3;
    *(f32x4*)(rp + 4 * 256) = accB0;
    *(f32x4*)(rp + 5 * 256) = accB1;
    *(f32x4*)(rp + 6 * 256) = accB2;
    *(f32x4*)(rp + 7 * 256) = accB3;
  }
  __syncthreads();
  if (h == 0) {
    const float* rp = (const float*)smem + rg * 2048 + lane * 4;
    accA0 += *(const f32x4*)(rp + 0 * 256);
    accA1 += *(const f32x4*)(rp + 1 * 256);
    accA2 += *(const f32x4*)(rp + 2 * 256);
    accA3 += *(const f32x4*)(rp + 3 * 256);
    accB0 += *(const f32x4*)(rp + 4 * 256);
    accB1 += *(const f32x4*)(rp + 5 * 256);
    accB2 += *(const f32x4*)(rp + 6 * 256);
    accB3 += *(const f32x4*)(rp + 7 * 256);

    const float bv0 = bias[lm];
    const float bv1 = bias[16 + lm];
    const float bv2 = bias[32 + lm];
    const float bv3 = bias[48 + lm];
    float* op = out + (size_t)b * NV * 64;
    #pragma unroll
    for (int mt = 0; mt < 2; ++mt) {
      const int gv = rbase + rg * 32 + mt * 16 + lk * 4;
      #pragma unroll
      for (int r = 0; r < 4; ++r) {
        float* orow = op + (size_t)(gv + r) * 64;
        if (mt == 0) {
          orow[lm]      = fmaxf(accA0[r] + bv0, 0.f);
          orow[16 + lm] = fmaxf(accA1[r] + bv1, 0.f);
          orow[32 + lm] = fmaxf(accA2[r] + bv2, 0.f);
          orow[48 + lm] = fmaxf(accA3[r] + bv3, 0.f);
        } else {
          orow[lm]      = fmaxf(accB0[r] + bv0, 0.f);
          orow[16 + lm] = fmaxf(accB1[r] + bv1, 0.f);
          orow[32 + lm] = fmaxf(accB2[r] + bv2, 0.f);
          orow[48 + lm] = fmaxf(accB3[r] + bv3, 0.f);
        }
      }
    }
  }
}

extern "C" void kernel_launch(void* const* d_in, const int* in_sizes, int n_in,
                              void* d_out, int out_size, void* d_ws, size_t ws_size,
                              hipStream_t stream) {
  const int* nbr = (const int*)d_in[0];
  // d_in[1] = vertices (unused by the reference computation)
  const float* fm = (const float*)d_in[2];
  const float* w = (const float*)d_in[3];
  const float* bias = (const float*)d_in[4];
  float* out = (float*)d_out;

  unsigned short* fmb = (unsigned short*)d_ws;          // 8*4096*64 bf16 = 4 MB
  unsigned short* wb = fmb + (size_t)8 * NV * 64;       // 17*64*64 bf16

  prep<<<1296, 256, 0, stream>>>(fm, w, fmb, wb);
  conv_main<<<512, 256, 0, stream>>>(nbr, fmb, wb, bias, out);
}